// Round 6
// baseline (1370.989 us; speedup 1.0000x reference)
//
#include <hip/hip_runtime.h>

#define F 128
#define BN 64

// ---------------- CSR build ----------------

__global__ __launch_bounds__(256) void count_kernel(const int* __restrict__ dst,
                                                    int* __restrict__ cnt, int e) {
    int i = blockIdx.x * 256 + threadIdx.x;
    if (i < e) atomicAdd(&cnt[dst[i]], 1);
}

__global__ __launch_bounds__(256) void dinv_kernel(const int* __restrict__ cnt,
                                                   float* __restrict__ dinv, int n) {
    int i = blockIdx.x * 256 + threadIdx.x;
    if (i < n) dinv[i] = rsqrtf((float)(cnt[i] + 1));  // +1 self loop
}

__global__ __launch_bounds__(1024) void scan_kernel(const int* __restrict__ cnt,
                                                    int* __restrict__ offs, int n) {
    __shared__ int sm[1024];
    int tid = threadIdx.x;
    int chunk = (n + 1023) >> 10;
    int b = tid * chunk;
    int e = b + chunk; if (e > n) e = n;
    int s = 0;
    for (int i = b; i < e; i++) s += cnt[i];
    sm[tid] = s;
    __syncthreads();
    for (int d = 1; d < 1024; d <<= 1) {
        int v = 0;
        if (tid >= d) v = sm[tid - d];
        __syncthreads();
        if (tid >= d) sm[tid] += v;
        __syncthreads();
    }
    int run = (tid == 0) ? 0 : sm[tid - 1];
    for (int i = b; i < e; i++) { offs[i] = run; run += cnt[i]; }
    if (tid == 1023) offs[n] = sm[1023];
}

__global__ __launch_bounds__(256) void fill_kernel(const int* __restrict__ src,
                                                   const int* __restrict__ dst,
                                                   const int* __restrict__ offs,
                                                   int* __restrict__ cursor,
                                                   const float* __restrict__ dinv,
                                                   int2* __restrict__ csr, int e) {
    int i = blockIdx.x * 256 + threadIdx.x;
    if (i >= e) return;
    int s = src[i], d = dst[i];
    int pos = atomicAdd(&cursor[d], 1);
    int2 pk;
    pk.x = s;
    pk.y = __float_as_int(dinv[s] * dinv[d]);
    csr[offs[d] + pos] = pk;
}

// ---------------- bf16 helpers ----------------

__device__ __forceinline__ unsigned short f32_to_bf16_rne(float x) {
    unsigned u = __float_as_uint(x);
    unsigned r = (u + 0x7fffu + ((u >> 16) & 1u)) >> 16;   // round to nearest even
    return (unsigned short)r;
}

__device__ __forceinline__ float bfhi(unsigned v) { return __uint_as_float(v & 0xffff0000u); }
__device__ __forceinline__ float bflo(unsigned v) { return __uint_as_float(v << 16); }

// ---------------- GEMM: outb[n][128](bf16) = h[n][128](f32) @ W[128][128] ----------------

__global__ __launch_bounds__(256) void gemm_kernel(const float* __restrict__ h,
                                                   const float* __restrict__ W,
                                                   unsigned short* __restrict__ outb, int n) {
    __shared__ float Ws[128 * 64];   // Ws[k][fh]
    __shared__ float Hs[BN * 128];   // Hs[nn][k ^ ((nn&7)<<2)]  (bank swizzle)
    const int tid = threadIdx.x;
    const int half = blockIdx.y;

    for (int i = tid; i < 128 * 64; i += 256) {
        int k = i >> 6, fh = i & 63;
        Ws[i] = W[k * F + (half << 6) + fh];
    }

    const int fg = tid & 15;
    const int ng = tid >> 4;
    const int f0 = fg << 2;
    const int n0 = ng << 2;
    const int nchunk = (n + BN - 1) / BN;

    for (int c = blockIdx.x; c < nchunk; c += gridDim.x) {
        const int base = c * BN;
        __syncthreads();
        for (int i = tid; i < BN * 128; i += 256) {
            int nn = i >> 7, k = i & 127;
            int node = base + nn;
            float v = (node < n) ? h[(size_t)node * F + k] : 0.0f;
            Hs[(nn << 7) + (k ^ ((nn & 7) << 2))] = v;
        }
        __syncthreads();

        float acc[4][4];
        #pragma unroll
        for (int a = 0; a < 4; a++)
            #pragma unroll
            for (int b = 0; b < 4; b++) acc[a][b] = 0.0f;

        #pragma unroll 2
        for (int kk = 0; kk < 128; kk += 4) {
            float4 w0 = *(const float4*)&Ws[((kk + 0) << 6) + f0];
            float4 w1 = *(const float4*)&Ws[((kk + 1) << 6) + f0];
            float4 w2 = *(const float4*)&Ws[((kk + 2) << 6) + f0];
            float4 w3 = *(const float4*)&Ws[((kk + 3) << 6) + f0];
            #pragma unroll
            for (int j = 0; j < 4; j++) {
                const int nn = n0 + j;
                float4 hv = *(const float4*)&Hs[(nn << 7) + (kk ^ ((nn & 7) << 2))];
                acc[j][0] += hv.x * w0.x + hv.y * w1.x + hv.z * w2.x + hv.w * w3.x;
                acc[j][1] += hv.x * w0.y + hv.y * w1.y + hv.z * w2.y + hv.w * w3.y;
                acc[j][2] += hv.x * w0.z + hv.y * w1.z + hv.z * w2.z + hv.w * w3.z;
                acc[j][3] += hv.x * w0.w + hv.y * w1.w + hv.z * w2.w + hv.w * w3.w;
            }
        }

        #pragma unroll
        for (int j = 0; j < 4; j++) {
            int node = base + n0 + j;
            if (node < n) {
                ushort4 v;
                v.x = f32_to_bf16_rne(acc[j][0]);
                v.y = f32_to_bf16_rne(acc[j][1]);
                v.z = f32_to_bf16_rne(acc[j][2]);
                v.w = f32_to_bf16_rne(acc[j][3]);
                *(ushort4*)&outb[(size_t)node * F + (half << 6) + f0] = v;
            }
        }
    }
}

// ---------------- Aggregate: wave-per-node, half-wave-per-edge (2 rows / instruction) ----
// hlb rows are bf16 [n][128] = [n][32] uint2. Lane l<32 -> even edges, l>=32 -> odd edges.
// Lane covers features 4*(l&31) .. 4*(l&31)+3, accumulated in f32; halves combined by shfl.

template <int POOL>
__global__ __launch_bounds__(256) void agg_kernel(const uint2* __restrict__ hlb2,
                                                  const int* __restrict__ offs,
                                                  const int2* __restrict__ csr,
                                                  const float* __restrict__ dinv,
                                                  const float* __restrict__ bias,
                                                  float* __restrict__ out,
                                                  const int* __restrict__ batch, int n) {
    const int lane  = threadIdx.x & 63;
    const int half  = lane >> 5;
    const int lane5 = lane & 31;
    const int i = blockIdx.x * 4 + (threadIdx.x >> 6);   // wave id == node id
    if (i >= n) return;

    float a0 = 0.0f, a1 = 0.0f, a2 = 0.0f, a3 = 0.0f;
    const int e0 = offs[i], e1 = offs[i + 1];
    int e = e0;

    // 8 edges per iteration: each half-wave takes alternate edges, 4 each.
    for (; e + 8 <= e1; e += 8) {
        #pragma unroll
        for (int u = 0; u < 4; u++) {
            int2 c = csr[e + 2 * u + half];
            uint2 r = hlb2[(size_t)c.x * 32 + lane5];
            float nf = __int_as_float(c.y);
            a0 += bflo(r.x) * nf;
            a1 += bfhi(r.x) * nf;
            a2 += bflo(r.y) * nf;
            a3 += bfhi(r.y) * nf;
        }
    }
    // pair remainder
    for (; e + 2 <= e1; e += 2) {
        int2 c = csr[e + half];
        uint2 r = hlb2[(size_t)c.x * 32 + lane5];
        float nf = __int_as_float(c.y);
        a0 += bflo(r.x) * nf;
        a1 += bfhi(r.x) * nf;
        a2 += bflo(r.y) * nf;
        a3 += bfhi(r.y) * nf;
    }
    // odd leftover edge -> half 0 only
    if (e < e1 && half == 0) {
        int2 c = csr[e];
        uint2 r = hlb2[(size_t)c.x * 32 + lane5];
        float nf = __int_as_float(c.y);
        a0 += bflo(r.x) * nf;
        a1 += bfhi(r.x) * nf;
        a2 += bflo(r.y) * nf;
        a3 += bfhi(r.y) * nf;
    }
    // self loop -> half 0 only
    if (half == 0) {
        float di = dinv[i];
        float w = di * di;
        uint2 r = hlb2[(size_t)i * 32 + lane5];
        a0 += bflo(r.x) * w;
        a1 += bfhi(r.x) * w;
        a2 += bflo(r.y) * w;
        a3 += bfhi(r.y) * w;
    }

    // combine halves: lane l (<32) += lane l+32
    a0 += __shfl(a0, (lane + 32) & 63, 64);
    a1 += __shfl(a1, (lane + 32) & 63, 64);
    a2 += __shfl(a2, (lane + 32) & 63, 64);
    a3 += __shfl(a3, (lane + 32) & 63, 64);

    if (half == 0) {
        float4 bv = *(const float4*)&bias[lane5 << 2];
        float r0 = fmaxf(a0 + bv.x, 0.0f);
        float r1 = fmaxf(a1 + bv.y, 0.0f);
        float r2 = fmaxf(a2 + bv.z, 0.0f);
        float r3 = fmaxf(a3 + bv.w, 0.0f);
        if (POOL) {
            int g = batch[i];
            int* op = (int*)&out[(size_t)g * F + (lane5 << 2)];
            atomicMax(op + 0, __float_as_int(r0));
            atomicMax(op + 1, __float_as_int(r1));
            atomicMax(op + 2, __float_as_int(r2));
            atomicMax(op + 3, __float_as_int(r3));
        } else {
            *(float4*)&out[(size_t)i * F + (lane5 << 2)] = make_float4(r0, r1, r2, r3);
        }
    }
}

// ---------------- MLP head + log_softmax ----------------

__global__ __launch_bounds__(128) void mlp_kernel(const float* __restrict__ pooled,
                                                  const float* __restrict__ Wp1,
                                                  const float* __restrict__ bp1,
                                                  const float* __restrict__ Wp2,
                                                  const float* __restrict__ bp2,
                                                  float* __restrict__ out) {
    __shared__ float pl[F];
    __shared__ float s0[2], s1[2];
    int g = blockIdx.x, t = threadIdx.x;
    pl[t] = pooled[(size_t)g * F + t];
    __syncthreads();
    float a = bp1[t];
    #pragma unroll 8
    for (int k = 0; k < F; k++) a += pl[k] * Wp1[k * F + t];
    float p0 = a * Wp2[t * 2 + 0];
    float p1 = a * Wp2[t * 2 + 1];
    #pragma unroll
    for (int d = 32; d > 0; d >>= 1) {
        p0 += __shfl_down(p0, d, 64);
        p1 += __shfl_down(p1, d, 64);
    }
    if ((t & 63) == 0) { s0[t >> 6] = p0; s1[t >> 6] = p1; }
    __syncthreads();
    if (t == 0) {
        float l0 = s0[0] + s0[1] + bp2[0];
        float l1 = s1[0] + s1[1] + bp2[1];
        float m = fmaxf(l0, l1);
        float lse = m + logf(expf(l0 - m) + expf(l1 - m));
        out[g * 2 + 0] = l0 - lse;
        out[g * 2 + 1] = l1 - lse;
    }
}

// ---------------- launch ----------------

extern "C" void kernel_launch(void* const* d_in, const int* in_sizes, int n_in,
                              void* d_out, int out_size, void* d_ws, size_t ws_size,
                              hipStream_t stream) {
    const float* x    = (const float*)d_in[0];
    const int*   ei   = (const int*)d_in[1];
    const int*   batch= (const int*)d_in[2];
    const float* W1 = (const float*)d_in[3];  const float* b1 = (const float*)d_in[4];
    const float* W2 = (const float*)d_in[5];  const float* b2 = (const float*)d_in[6];
    const float* W3 = (const float*)d_in[7];  const float* b3 = (const float*)d_in[8];
    const float* Wp1= (const float*)d_in[9];  const float* bp1= (const float*)d_in[10];
    const float* Wp2= (const float*)d_in[11]; const float* bp2= (const float*)d_in[12];

    const int N = in_sizes[0] / F;
    const int E = in_sizes[1] / 2;
    const int G = out_size / 2;

    char* w = (char*)d_ws;
    size_t off = 0;
    auto alloc = [&](size_t bytes) -> void* {
        void* p = w + off;
        off = (off + bytes + 255) & ~(size_t)255;
        return p;
    };
    unsigned short* hlb = (unsigned short*)alloc((size_t)N * F * 2);  // bf16 GEMM out
    float* hbuf   = (float*)alloc((size_t)N * F * 4);                 // f32 agg out
    int*   deg    = (int*)alloc((size_t)N * 4);
    int*   cursor = (int*)alloc((size_t)N * 4);
    int*   offs   = (int*)alloc((size_t)(N + 1) * 4);
    float* dinv   = (float*)alloc((size_t)N * 4);
    int2*  csr    = (int2*)alloc((size_t)E * 8);
    float* pooled = (float*)alloc((size_t)G * F * 4);

    const int* srcp = ei;
    const int* dstp = ei + E;

    hipMemsetAsync(deg,    0, (size_t)N * 4, stream);
    hipMemsetAsync(cursor, 0, (size_t)N * 4, stream);
    hipMemsetAsync(pooled, 0, (size_t)G * F * 4, stream);

    const int eb = (E + 255) / 256;
    const int nb = (N + 255) / 256;
    count_kernel<<<eb, 256, 0, stream>>>(dstp, deg, E);
    dinv_kernel<<<nb, 256, 0, stream>>>(deg, dinv, N);
    scan_kernel<<<1, 1024, 0, stream>>>(deg, offs, N);
    fill_kernel<<<eb, 256, 0, stream>>>(srcp, dstp, offs, cursor, dinv, csr, E);

    const int ab = (N + 3) / 4;   // 4 waves (nodes) per block
    dim3 gg(512, 2);
    gemm_kernel<<<gg, 256, 0, stream>>>(x, W1, hlb, N);
    agg_kernel<0><<<ab, 256, 0, stream>>>((const uint2*)hlb, offs, csr, dinv, b1, hbuf, nullptr, N);
    gemm_kernel<<<gg, 256, 0, stream>>>(hbuf, W2, hlb, N);
    agg_kernel<0><<<ab, 256, 0, stream>>>((const uint2*)hlb, offs, csr, dinv, b2, hbuf, nullptr, N);
    gemm_kernel<<<gg, 256, 0, stream>>>(hbuf, W3, hlb, N);
    agg_kernel<1><<<ab, 256, 0, stream>>>((const uint2*)hlb, offs, csr, dinv, b3, pooled, batch, N);
    mlp_kernel<<<G, 128, 0, stream>>>(pooled, Wp1, bp1, Wp2, bp2, (float*)d_out);
}

// Round 7
// 1153.829 us; speedup vs baseline: 1.1882x; 1.1882x over previous
//
#include <hip/hip_runtime.h>

#define F 128
#define BN 64

// ---------------- CSR build ----------------

__global__ __launch_bounds__(256) void count_kernel(const int* __restrict__ dst,
                                                    int* __restrict__ cnt, int e) {
    int i = blockIdx.x * 256 + threadIdx.x;
    if (i < e) atomicAdd(&cnt[dst[i]], 1);
}

__global__ __launch_bounds__(256) void dinv_kernel(const int* __restrict__ cnt,
                                                   float* __restrict__ dinv, int n) {
    int i = blockIdx.x * 256 + threadIdx.x;
    if (i < n) dinv[i] = rsqrtf((float)(cnt[i] + 1));  // +1 self loop
}

__global__ __launch_bounds__(1024) void scan_kernel(const int* __restrict__ cnt,
                                                    int* __restrict__ offs, int n) {
    __shared__ int sm[1024];
    int tid = threadIdx.x;
    int chunk = (n + 1023) >> 10;
    int b = tid * chunk;
    int e = b + chunk; if (e > n) e = n;
    int s = 0;
    for (int i = b; i < e; i++) s += cnt[i];
    sm[tid] = s;
    __syncthreads();
    for (int d = 1; d < 1024; d <<= 1) {
        int v = 0;
        if (tid >= d) v = sm[tid - d];
        __syncthreads();
        if (tid >= d) sm[tid] += v;
        __syncthreads();
    }
    int run = (tid == 0) ? 0 : sm[tid - 1];
    for (int i = b; i < e; i++) { offs[i] = run; run += cnt[i]; }
    if (tid == 1023) offs[n] = sm[1023];
}

__global__ __launch_bounds__(256) void fill_kernel(const int* __restrict__ src,
                                                   const int* __restrict__ dst,
                                                   const int* __restrict__ offs,
                                                   int* __restrict__ cursor,
                                                   const float* __restrict__ dinv,
                                                   int2* __restrict__ csr, int e) {
    int i = blockIdx.x * 256 + threadIdx.x;
    if (i >= e) return;
    int s = src[i], d = dst[i];
    int pos = atomicAdd(&cursor[d], 1);
    int2 pk;
    pk.x = s;
    pk.y = __float_as_int(dinv[s] * dinv[d]);
    csr[offs[d] + pos] = pk;
}

// ---------------- bf16 helpers ----------------

__device__ __forceinline__ unsigned short f32_to_bf16_rne(float x) {
    unsigned u = __float_as_uint(x);
    unsigned r = (u + 0x7fffu + ((u >> 16) & 1u)) >> 16;   // round to nearest even
    return (unsigned short)r;
}

__device__ __forceinline__ float bfhi(unsigned v) { return __uint_as_float(v & 0xffff0000u); }
__device__ __forceinline__ float bflo(unsigned v) { return __uint_as_float(v << 16); }

// ---------------- GEMM: outb[n][128](bf16) = h[n][128](f32) @ W[128][128] ----------------

__global__ __launch_bounds__(256) void gemm_kernel(const float* __restrict__ h,
                                                   const float* __restrict__ W,
                                                   unsigned short* __restrict__ outb, int n) {
    __shared__ float Ws[128 * 64];   // Ws[k][fh]
    __shared__ float Hs[BN * 128];   // Hs[nn][k ^ ((nn&7)<<2)]  (bank swizzle)
    const int tid = threadIdx.x;
    const int half = blockIdx.y;

    for (int i = tid; i < 128 * 64; i += 256) {
        int k = i >> 6, fh = i & 63;
        Ws[i] = W[k * F + (half << 6) + fh];
    }

    const int fg = tid & 15;
    const int ng = tid >> 4;
    const int f0 = fg << 2;
    const int n0 = ng << 2;
    const int nchunk = (n + BN - 1) / BN;

    for (int c = blockIdx.x; c < nchunk; c += gridDim.x) {
        const int base = c * BN;
        __syncthreads();
        for (int i = tid; i < BN * 128; i += 256) {
            int nn = i >> 7, k = i & 127;
            int node = base + nn;
            float v = (node < n) ? h[(size_t)node * F + k] : 0.0f;
            Hs[(nn << 7) + (k ^ ((nn & 7) << 2))] = v;
        }
        __syncthreads();

        float acc[4][4];
        #pragma unroll
        for (int a = 0; a < 4; a++)
            #pragma unroll
            for (int b = 0; b < 4; b++) acc[a][b] = 0.0f;

        #pragma unroll 2
        for (int kk = 0; kk < 128; kk += 4) {
            float4 w0 = *(const float4*)&Ws[((kk + 0) << 6) + f0];
            float4 w1 = *(const float4*)&Ws[((kk + 1) << 6) + f0];
            float4 w2 = *(const float4*)&Ws[((kk + 2) << 6) + f0];
            float4 w3 = *(const float4*)&Ws[((kk + 3) << 6) + f0];
            #pragma unroll
            for (int j = 0; j < 4; j++) {
                const int nn = n0 + j;
                float4 hv = *(const float4*)&Hs[(nn << 7) + (kk ^ ((nn & 7) << 2))];
                acc[j][0] += hv.x * w0.x + hv.y * w1.x + hv.z * w2.x + hv.w * w3.x;
                acc[j][1] += hv.x * w0.y + hv.y * w1.y + hv.z * w2.y + hv.w * w3.y;
                acc[j][2] += hv.x * w0.z + hv.y * w1.z + hv.z * w2.z + hv.w * w3.z;
                acc[j][3] += hv.x * w0.w + hv.y * w1.w + hv.z * w2.w + hv.w * w3.w;
            }
        }

        #pragma unroll
        for (int j = 0; j < 4; j++) {
            int node = base + n0 + j;
            if (node < n) {
                ushort4 v;
                v.x = f32_to_bf16_rne(acc[j][0]);
                v.y = f32_to_bf16_rne(acc[j][1]);
                v.z = f32_to_bf16_rne(acc[j][2]);
                v.w = f32_to_bf16_rne(acc[j][3]);
                *(ushort4*)&outb[(size_t)node * F + (half << 6) + f0] = v;
            }
        }
    }
}

// ---------------- Aggregate: persistent wave-per-node, csr software pipeline ----------------
// hlb rows bf16 [n][64] dwords; lane covers 2 feats. Batch of 8 rows in flight;
// next batch's csr entries issued before waiting on current rows.

template <int POOL>
__global__ __launch_bounds__(256) void agg_kernel(const unsigned* __restrict__ hlb,
                                                  const int* __restrict__ offs,
                                                  const int2* __restrict__ csr,
                                                  const float* __restrict__ dinv,
                                                  const float* __restrict__ bias,
                                                  float* __restrict__ out,
                                                  const int* __restrict__ batch, int n) {
    const int lane = threadIdx.x & 63;
    const int wstart = blockIdx.x * 4 + (threadIdx.x >> 6);
    const int wstride = gridDim.x * 4;
    const unsigned* __restrict__ rowp = hlb + lane;
    const float2 bv = ((const float2*)bias)[lane];

    for (int i = wstart; i < n; i += wstride) {
        float ax = 0.0f, ay = 0.0f;
        const int e0 = offs[i], e1 = offs[i + 1];
        int nb = (e1 - e0) >> 3;            // number of full 8-batches

        int2 cc0, cc1, cc2, cc3, cc4, cc5, cc6, cc7;
        int e = e0;
        if (nb > 0) {                       // prologue: csr batch 0
            cc0 = csr[e + 0]; cc1 = csr[e + 1]; cc2 = csr[e + 2]; cc3 = csr[e + 3];
            cc4 = csr[e + 4]; cc5 = csr[e + 5]; cc6 = csr[e + 6]; cc7 = csr[e + 7];
        }
        for (int b = 0; b < nb; b++) {
            // issue row loads for current batch
            unsigned r0 = rowp[(size_t)cc0.x << 6];
            unsigned r1 = rowp[(size_t)cc1.x << 6];
            unsigned r2 = rowp[(size_t)cc2.x << 6];
            unsigned r3 = rowp[(size_t)cc3.x << 6];
            unsigned r4 = rowp[(size_t)cc4.x << 6];
            unsigned r5 = rowp[(size_t)cc5.x << 6];
            unsigned r6 = rowp[(size_t)cc6.x << 6];
            unsigned r7 = rowp[(size_t)cc7.x << 6];
            float n0 = __int_as_float(cc0.y), n1 = __int_as_float(cc1.y);
            float n2 = __int_as_float(cc2.y), n3 = __int_as_float(cc3.y);
            float n4 = __int_as_float(cc4.y), n5 = __int_as_float(cc5.y);
            float n6 = __int_as_float(cc6.y), n7 = __int_as_float(cc7.y);
            // issue next batch's csr loads before consuming rows
            e += 8;
            if (b + 1 < nb) {
                cc0 = csr[e + 0]; cc1 = csr[e + 1]; cc2 = csr[e + 2]; cc3 = csr[e + 3];
                cc4 = csr[e + 4]; cc5 = csr[e + 5]; cc6 = csr[e + 6]; cc7 = csr[e + 7];
            }
            // consume rows
            ax += bflo(r0) * n0 + bflo(r1) * n1 + bflo(r2) * n2 + bflo(r3) * n3
                + bflo(r4) * n4 + bflo(r5) * n5 + bflo(r6) * n6 + bflo(r7) * n7;
            ay += bfhi(r0) * n0 + bfhi(r1) * n1 + bfhi(r2) * n2 + bfhi(r3) * n3
                + bfhi(r4) * n4 + bfhi(r5) * n5 + bfhi(r6) * n6 + bfhi(r7) * n7;
        }
        // remainder
        for (; e < e1; e++) {
            int2 c = csr[e];
            unsigned r = rowp[(size_t)c.x << 6];
            float nf = __int_as_float(c.y);
            ax += bflo(r) * nf;
            ay += bfhi(r) * nf;
        }
        // self loop
        {
            float di = dinv[i];
            unsigned r = rowp[(size_t)i << 6];
            ax += bflo(r) * di * di;
            ay += bfhi(r) * di * di;
        }

        float rx = fmaxf(ax + bv.x, 0.0f);
        float ry = fmaxf(ay + bv.y, 0.0f);
        if (POOL) {
            int g = batch[i];
            atomicMax((int*)&out[(size_t)g * F + 2 * lane + 0], __float_as_int(rx));
            atomicMax((int*)&out[(size_t)g * F + 2 * lane + 1], __float_as_int(ry));
        } else {
            ((float2*)out)[(size_t)i * 64 + lane] = make_float2(rx, ry);
        }
    }
}

// ---------------- MLP head + log_softmax ----------------

__global__ __launch_bounds__(128) void mlp_kernel(const float* __restrict__ pooled,
                                                  const float* __restrict__ Wp1,
                                                  const float* __restrict__ bp1,
                                                  const float* __restrict__ Wp2,
                                                  const float* __restrict__ bp2,
                                                  float* __restrict__ out) {
    __shared__ float pl[F];
    __shared__ float s0[2], s1[2];
    int g = blockIdx.x, t = threadIdx.x;
    pl[t] = pooled[(size_t)g * F + t];
    __syncthreads();
    float a = bp1[t];
    #pragma unroll 8
    for (int k = 0; k < F; k++) a += pl[k] * Wp1[k * F + t];
    float p0 = a * Wp2[t * 2 + 0];
    float p1 = a * Wp2[t * 2 + 1];
    #pragma unroll
    for (int d = 32; d > 0; d >>= 1) {
        p0 += __shfl_down(p0, d, 64);
        p1 += __shfl_down(p1, d, 64);
    }
    if ((t & 63) == 0) { s0[t >> 6] = p0; s1[t >> 6] = p1; }
    __syncthreads();
    if (t == 0) {
        float l0 = s0[0] + s0[1] + bp2[0];
        float l1 = s1[0] + s1[1] + bp2[1];
        float m = fmaxf(l0, l1);
        float lse = m + logf(expf(l0 - m) + expf(l1 - m));
        out[g * 2 + 0] = l0 - lse;
        out[g * 2 + 1] = l1 - lse;
    }
}

// ---------------- launch ----------------

extern "C" void kernel_launch(void* const* d_in, const int* in_sizes, int n_in,
                              void* d_out, int out_size, void* d_ws, size_t ws_size,
                              hipStream_t stream) {
    const float* x    = (const float*)d_in[0];
    const int*   ei   = (const int*)d_in[1];
    const int*   batch= (const int*)d_in[2];
    const float* W1 = (const float*)d_in[3];  const float* b1 = (const float*)d_in[4];
    const float* W2 = (const float*)d_in[5];  const float* b2 = (const float*)d_in[6];
    const float* W3 = (const float*)d_in[7];  const float* b3 = (const float*)d_in[8];
    const float* Wp1= (const float*)d_in[9];  const float* bp1= (const float*)d_in[10];
    const float* Wp2= (const float*)d_in[11]; const float* bp2= (const float*)d_in[12];

    const int N = in_sizes[0] / F;
    const int E = in_sizes[1] / 2;
    const int G = out_size / 2;

    char* w = (char*)d_ws;
    size_t off = 0;
    auto alloc = [&](size_t bytes) -> void* {
        void* p = w + off;
        off = (off + bytes + 255) & ~(size_t)255;
        return p;
    };
    unsigned short* hlb = (unsigned short*)alloc((size_t)N * F * 2);  // bf16 GEMM out
    float* hbuf   = (float*)alloc((size_t)N * F * 4);                 // f32 agg out
    int*   deg    = (int*)alloc((size_t)N * 4);
    int*   cursor = (int*)alloc((size_t)N * 4);
    int*   offs   = (int*)alloc((size_t)(N + 1) * 4);
    float* dinv   = (float*)alloc((size_t)N * 4);
    int2*  csr    = (int2*)alloc((size_t)E * 8);
    float* pooled = (float*)alloc((size_t)G * F * 4);

    const int* srcp = ei;
    const int* dstp = ei + E;

    hipMemsetAsync(deg,    0, (size_t)N * 4, stream);
    hipMemsetAsync(cursor, 0, (size_t)N * 4, stream);
    hipMemsetAsync(pooled, 0, (size_t)G * F * 4, stream);

    const int eb = (E + 255) / 256;
    const int nb = (N + 255) / 256;
    count_kernel<<<eb, 256, 0, stream>>>(dstp, deg, E);
    dinv_kernel<<<nb, 256, 0, stream>>>(deg, dinv, N);
    scan_kernel<<<1, 1024, 0, stream>>>(deg, offs, N);
    fill_kernel<<<eb, 256, 0, stream>>>(srcp, dstp, offs, cursor, dinv, csr, E);

    const int ab = 2048;   // persistent: 8 blocks/CU * 256 CUs
    dim3 gg(512, 2);
    gemm_kernel<<<gg, 256, 0, stream>>>(x, W1, hlb, N);
    agg_kernel<0><<<ab, 256, 0, stream>>>((const unsigned*)hlb, offs, csr, dinv, b1, hbuf, nullptr, N);
    gemm_kernel<<<gg, 256, 0, stream>>>(hbuf, W2, hlb, N);
    agg_kernel<0><<<ab, 256, 0, stream>>>((const unsigned*)hlb, offs, csr, dinv, b2, hbuf, nullptr, N);
    gemm_kernel<<<gg, 256, 0, stream>>>(hbuf, W3, hlb, N);
    agg_kernel<1><<<ab, 256, 0, stream>>>((const unsigned*)hlb, offs, csr, dinv, b3, pooled, batch, N);
    mlp_kernel<<<G, 128, 0, stream>>>(pooled, Wp1, bp1, Wp2, bp2, (float*)d_out);
}

// Round 8
// 1153.714 us; speedup vs baseline: 1.1883x; 1.0001x over previous
//
#include <hip/hip_runtime.h>

#define F 128
#define BN 64

// ---------------- common build kernels ----------------

__global__ __launch_bounds__(256) void count2_kernel(const int* __restrict__ src,
                                                     const int* __restrict__ dst,
                                                     int* __restrict__ cntd,
                                                     int* __restrict__ cnts, int e) {
    int i = blockIdx.x * 256 + threadIdx.x;
    if (i < e) {
        atomicAdd(&cntd[dst[i]], 1);
        if (cnts) atomicAdd(&cnts[src[i]], 1);
    }
}

__global__ __launch_bounds__(256) void dinv_kernel(const int* __restrict__ cnt,
                                                   float* __restrict__ dinv, int n) {
    int i = blockIdx.x * 256 + threadIdx.x;
    if (i < n) dinv[i] = rsqrtf((float)(cnt[i] + 1));  // +1 self loop
}

__global__ __launch_bounds__(1024) void scan_kernel(const int* __restrict__ cnt,
                                                    int* __restrict__ offs, int n) {
    __shared__ int sm[1024];
    int tid = threadIdx.x;
    int chunk = (n + 1023) >> 10;
    int b = tid * chunk;
    int e = b + chunk; if (e > n) e = n;
    int s = 0;
    for (int i = b; i < e; i++) s += cnt[i];
    sm[tid] = s;
    __syncthreads();
    for (int d = 1; d < 1024; d <<= 1) {
        int v = 0;
        if (tid >= d) v = sm[tid - d];
        __syncthreads();
        if (tid >= d) sm[tid] += v;
        __syncthreads();
    }
    int run = (tid == 0) ? 0 : sm[tid - 1];
    for (int i = b; i < e; i++) { offs[i] = run; run += cnt[i]; }
    if (tid == 1023) offs[n] = sm[1023];
}

// primary: build CSC entries (slot in CSR(dst) order, norm)
__global__ __launch_bounds__(256) void fill2_kernel(const int* __restrict__ src,
                                                    const int* __restrict__ dst,
                                                    const int* __restrict__ offs,
                                                    const int* __restrict__ soffs,
                                                    int* __restrict__ curd,
                                                    int* __restrict__ curs,
                                                    const float* __restrict__ dinv,
                                                    int2* __restrict__ csc, int e) {
    int i = blockIdx.x * 256 + threadIdx.x;
    if (i >= e) return;
    int s = src[i], d = dst[i];
    int slot = offs[d] + atomicAdd(&curd[d], 1);
    int cpos = soffs[s] + atomicAdd(&curs[s], 1);
    csc[cpos] = make_int2(slot, __float_as_int(dinv[s] * dinv[d]));
}

// fallback: CSR (src, norm)
__global__ __launch_bounds__(256) void fill_kernel(const int* __restrict__ src,
                                                   const int* __restrict__ dst,
                                                   const int* __restrict__ offs,
                                                   int* __restrict__ cursor,
                                                   const float* __restrict__ dinv,
                                                   int2* __restrict__ csr, int e) {
    int i = blockIdx.x * 256 + threadIdx.x;
    if (i >= e) return;
    int s = src[i], d = dst[i];
    int pos = atomicAdd(&cursor[d], 1);
    csr[offs[d] + pos] = make_int2(s, __float_as_int(dinv[s] * dinv[d]));
}

// ---------------- bf16 helpers ----------------

__device__ __forceinline__ unsigned short f32_to_bf16_rne(float x) {
    unsigned u = __float_as_uint(x);
    unsigned r = (u + 0x7fffu + ((u >> 16) & 1u)) >> 16;   // round to nearest even
    return (unsigned short)r;
}

__device__ __forceinline__ float bfhi(unsigned v) { return __uint_as_float(v & 0xffff0000u); }
__device__ __forceinline__ float bflo(unsigned v) { return __uint_as_float(v << 16); }

// ---------------- GEMM: out[n][128] = h[n][128](f32) @ W[128][128] ----------------

template <bool BF16OUT>
__global__ __launch_bounds__(256) void gemm_kernel(const float* __restrict__ h,
                                                   const float* __restrict__ W,
                                                   void* __restrict__ outp, int n) {
    __shared__ float Ws[128 * 64];   // Ws[k][fh]
    __shared__ float Hs[BN * 128];   // Hs[nn][k ^ ((nn&7)<<2)]  (bank swizzle)
    const int tid = threadIdx.x;
    const int half = blockIdx.y;

    for (int i = tid; i < 128 * 64; i += 256) {
        int k = i >> 6, fh = i & 63;
        Ws[i] = W[k * F + (half << 6) + fh];
    }

    const int fg = tid & 15;
    const int ng = tid >> 4;
    const int f0 = fg << 2;
    const int n0 = ng << 2;
    const int nchunk = (n + BN - 1) / BN;

    for (int c = blockIdx.x; c < nchunk; c += gridDim.x) {
        const int base = c * BN;
        __syncthreads();
        for (int i = tid; i < BN * 128; i += 256) {
            int nn = i >> 7, k = i & 127;
            int node = base + nn;
            float v = (node < n) ? h[(size_t)node * F + k] : 0.0f;
            Hs[(nn << 7) + (k ^ ((nn & 7) << 2))] = v;
        }
        __syncthreads();

        float acc[4][4];
        #pragma unroll
        for (int a = 0; a < 4; a++)
            #pragma unroll
            for (int b = 0; b < 4; b++) acc[a][b] = 0.0f;

        #pragma unroll 2
        for (int kk = 0; kk < 128; kk += 4) {
            float4 w0 = *(const float4*)&Ws[((kk + 0) << 6) + f0];
            float4 w1 = *(const float4*)&Ws[((kk + 1) << 6) + f0];
            float4 w2 = *(const float4*)&Ws[((kk + 2) << 6) + f0];
            float4 w3 = *(const float4*)&Ws[((kk + 3) << 6) + f0];
            #pragma unroll
            for (int j = 0; j < 4; j++) {
                const int nn = n0 + j;
                float4 hv = *(const float4*)&Hs[(nn << 7) + (kk ^ ((nn & 7) << 2))];
                acc[j][0] += hv.x * w0.x + hv.y * w1.x + hv.z * w2.x + hv.w * w3.x;
                acc[j][1] += hv.x * w0.y + hv.y * w1.y + hv.z * w2.y + hv.w * w3.y;
                acc[j][2] += hv.x * w0.z + hv.y * w1.z + hv.z * w2.z + hv.w * w3.z;
                acc[j][3] += hv.x * w0.w + hv.y * w1.w + hv.z * w2.w + hv.w * w3.w;
            }
        }

        #pragma unroll
        for (int j = 0; j < 4; j++) {
            int node = base + n0 + j;
            if (node < n) {
                if (BF16OUT) {
                    ushort4 v;
                    v.x = f32_to_bf16_rne(acc[j][0]);
                    v.y = f32_to_bf16_rne(acc[j][1]);
                    v.z = f32_to_bf16_rne(acc[j][2]);
                    v.w = f32_to_bf16_rne(acc[j][3]);
                    *(ushort4*)&((unsigned short*)outp)[(size_t)node * F + (half << 6) + f0] = v;
                } else {
                    float4 v = make_float4(acc[j][0], acc[j][1], acc[j][2], acc[j][3]);
                    *(float4*)&((float*)outp)[(size_t)node * F + (half << 6) + f0] = v;
                }
            }
        }
    }
}

// ---------------- PRIMARY Phase A: scatter messages (streaming reads, scattered writes) ----

__global__ __launch_bounds__(256) void scat_kernel(const float2* __restrict__ h2,
                                                   const int* __restrict__ soffs,
                                                   const int2* __restrict__ csc,
                                                   unsigned* __restrict__ msg, int n) {
    const int lane = threadIdx.x & 63;
    const int wstart = blockIdx.x * 4 + (threadIdx.x >> 6);
    const int wstride = gridDim.x * 4;
    for (int s = wstart; s < n; s += wstride) {
        float2 v = h2[(size_t)s * 64 + lane];
        const int e0 = soffs[s], e1 = soffs[s + 1];
        for (int e = e0; e < e1; e++) {
            int2 c = csc[e];
            float nf = __int_as_float(c.y);
            unsigned lo = (unsigned)f32_to_bf16_rne(v.x * nf);
            unsigned hi = (unsigned)f32_to_bf16_rne(v.y * nf);
            msg[(size_t)c.x * 64 + lane] = lo | (hi << 16);
        }
    }
}

// ---------------- PRIMARY Phase B: contiguous msg sum per dst node ----------------

template <int POOL>
__global__ __launch_bounds__(256) void aggB_kernel(const unsigned* __restrict__ msg,
                                                   const float2* __restrict__ h2,
                                                   const int* __restrict__ offs,
                                                   const float* __restrict__ dinv,
                                                   const float* __restrict__ bias,
                                                   float* __restrict__ out,
                                                   const int* __restrict__ batch, int n) {
    const int lane = threadIdx.x & 63;
    const int wstart = blockIdx.x * 4 + (threadIdx.x >> 6);
    const int wstride = gridDim.x * 4;
    const unsigned* __restrict__ rowp = msg + lane;
    const float2 bv = ((const float2*)bias)[lane];

    for (int i = wstart; i < n; i += wstride) {
        float ax = 0.0f, ay = 0.0f;
        const int e0 = offs[i], e1 = offs[i + 1];
        int e = e0;
        for (; e + 8 <= e1; e += 8) {
            unsigned r0 = rowp[(size_t)(e + 0) << 6];
            unsigned r1 = rowp[(size_t)(e + 1) << 6];
            unsigned r2 = rowp[(size_t)(e + 2) << 6];
            unsigned r3 = rowp[(size_t)(e + 3) << 6];
            unsigned r4 = rowp[(size_t)(e + 4) << 6];
            unsigned r5 = rowp[(size_t)(e + 5) << 6];
            unsigned r6 = rowp[(size_t)(e + 6) << 6];
            unsigned r7 = rowp[(size_t)(e + 7) << 6];
            ax += bflo(r0) + bflo(r1) + bflo(r2) + bflo(r3)
                + bflo(r4) + bflo(r5) + bflo(r6) + bflo(r7);
            ay += bfhi(r0) + bfhi(r1) + bfhi(r2) + bfhi(r3)
                + bfhi(r4) + bfhi(r5) + bfhi(r6) + bfhi(r7);
        }
        for (; e < e1; e++) {
            unsigned r = rowp[(size_t)e << 6];
            ax += bflo(r);
            ay += bfhi(r);
        }
        {   // self loop (sequential read)
            float di = dinv[i];
            float2 sv = h2[(size_t)i * 64 + lane];
            ax += sv.x * di * di;
            ay += sv.y * di * di;
        }
        float rx = fmaxf(ax + bv.x, 0.0f);
        float ry = fmaxf(ay + bv.y, 0.0f);
        if (POOL) {
            int g = batch[i];
            atomicMax((int*)&out[(size_t)g * F + 2 * lane + 0], __float_as_int(rx));
            atomicMax((int*)&out[(size_t)g * F + 2 * lane + 1], __float_as_int(ry));
        } else {
            ((float2*)out)[(size_t)i * 64 + lane] = make_float2(rx, ry);
        }
    }
}

// ---------------- FALLBACK aggregate (R7): persistent gather with csr pipeline ----------

template <int POOL>
__global__ __launch_bounds__(256) void agg_kernel(const unsigned* __restrict__ hlb,
                                                  const int* __restrict__ offs,
                                                  const int2* __restrict__ csr,
                                                  const float* __restrict__ dinv,
                                                  const float* __restrict__ bias,
                                                  float* __restrict__ out,
                                                  const int* __restrict__ batch, int n) {
    const int lane = threadIdx.x & 63;
    const int wstart = blockIdx.x * 4 + (threadIdx.x >> 6);
    const int wstride = gridDim.x * 4;
    const unsigned* __restrict__ rowp = hlb + lane;
    const float2 bv = ((const float2*)bias)[lane];

    for (int i = wstart; i < n; i += wstride) {
        float ax = 0.0f, ay = 0.0f;
        const int e0 = offs[i], e1 = offs[i + 1];
        int nb = (e1 - e0) >> 3;
        int2 cc0, cc1, cc2, cc3, cc4, cc5, cc6, cc7;
        int e = e0;
        if (nb > 0) {
            cc0 = csr[e + 0]; cc1 = csr[e + 1]; cc2 = csr[e + 2]; cc3 = csr[e + 3];
            cc4 = csr[e + 4]; cc5 = csr[e + 5]; cc6 = csr[e + 6]; cc7 = csr[e + 7];
        }
        for (int b = 0; b < nb; b++) {
            unsigned r0 = rowp[(size_t)cc0.x << 6];
            unsigned r1 = rowp[(size_t)cc1.x << 6];
            unsigned r2 = rowp[(size_t)cc2.x << 6];
            unsigned r3 = rowp[(size_t)cc3.x << 6];
            unsigned r4 = rowp[(size_t)cc4.x << 6];
            unsigned r5 = rowp[(size_t)cc5.x << 6];
            unsigned r6 = rowp[(size_t)cc6.x << 6];
            unsigned r7 = rowp[(size_t)cc7.x << 6];
            float n0 = __int_as_float(cc0.y), n1 = __int_as_float(cc1.y);
            float n2 = __int_as_float(cc2.y), n3 = __int_as_float(cc3.y);
            float n4 = __int_as_float(cc4.y), n5 = __int_as_float(cc5.y);
            float n6 = __int_as_float(cc6.y), n7 = __int_as_float(cc7.y);
            e += 8;
            if (b + 1 < nb) {
                cc0 = csr[e + 0]; cc1 = csr[e + 1]; cc2 = csr[e + 2]; cc3 = csr[e + 3];
                cc4 = csr[e + 4]; cc5 = csr[e + 5]; cc6 = csr[e + 6]; cc7 = csr[e + 7];
            }
            ax += bflo(r0) * n0 + bflo(r1) * n1 + bflo(r2) * n2 + bflo(r3) * n3
                + bflo(r4) * n4 + bflo(r5) * n5 + bflo(r6) * n6 + bflo(r7) * n7;
            ay += bfhi(r0) * n0 + bfhi(r1) * n1 + bfhi(r2) * n2 + bfhi(r3) * n3
                + bfhi(r4) * n4 + bfhi(r5) * n5 + bfhi(r6) * n6 + bfhi(r7) * n7;
        }
        for (; e < e1; e++) {
            int2 c = csr[e];
            unsigned r = rowp[(size_t)c.x << 6];
            float nf = __int_as_float(c.y);
            ax += bflo(r) * nf;
            ay += bfhi(r) * nf;
        }
        {
            float di = dinv[i];
            unsigned r = rowp[(size_t)i << 6];
            ax += bflo(r) * di * di;
            ay += bfhi(r) * di * di;
        }
        float rx = fmaxf(ax + bv.x, 0.0f);
        float ry = fmaxf(ay + bv.y, 0.0f);
        if (POOL) {
            int g = batch[i];
            atomicMax((int*)&out[(size_t)g * F + 2 * lane + 0], __float_as_int(rx));
            atomicMax((int*)&out[(size_t)g * F + 2 * lane + 1], __float_as_int(ry));
        } else {
            ((float2*)out)[(size_t)i * 64 + lane] = make_float2(rx, ry);
        }
    }
}

// ---------------- MLP head + log_softmax ----------------

__global__ __launch_bounds__(128) void mlp_kernel(const float* __restrict__ pooled,
                                                  const float* __restrict__ Wp1,
                                                  const float* __restrict__ bp1,
                                                  const float* __restrict__ Wp2,
                                                  const float* __restrict__ bp2,
                                                  float* __restrict__ out) {
    __shared__ float pl[F];
    __shared__ float s0[2], s1[2];
    int g = blockIdx.x, t = threadIdx.x;
    pl[t] = pooled[(size_t)g * F + t];
    __syncthreads();
    float a = bp1[t];
    #pragma unroll 8
    for (int k = 0; k < F; k++) a += pl[k] * Wp1[k * F + t];
    float p0 = a * Wp2[t * 2 + 0];
    float p1 = a * Wp2[t * 2 + 1];
    #pragma unroll
    for (int d = 32; d > 0; d >>= 1) {
        p0 += __shfl_down(p0, d, 64);
        p1 += __shfl_down(p1, d, 64);
    }
    if ((t & 63) == 0) { s0[t >> 6] = p0; s1[t >> 6] = p1; }
    __syncthreads();
    if (t == 0) {
        float l0 = s0[0] + s0[1] + bp2[0];
        float l1 = s1[0] + s1[1] + bp2[1];
        float m = fmaxf(l0, l1);
        float lse = m + logf(expf(l0 - m) + expf(l1 - m));
        out[g * 2 + 0] = l0 - lse;
        out[g * 2 + 1] = l1 - lse;
    }
}

// ---------------- launch ----------------

extern "C" void kernel_launch(void* const* d_in, const int* in_sizes, int n_in,
                              void* d_out, int out_size, void* d_ws, size_t ws_size,
                              hipStream_t stream) {
    const float* x    = (const float*)d_in[0];
    const int*   ei   = (const int*)d_in[1];
    const int*   batch= (const int*)d_in[2];
    const float* W1 = (const float*)d_in[3];  const float* b1 = (const float*)d_in[4];
    const float* W2 = (const float*)d_in[5];  const float* b2 = (const float*)d_in[6];
    const float* W3 = (const float*)d_in[7];  const float* b3 = (const float*)d_in[8];
    const float* Wp1= (const float*)d_in[9];  const float* bp1= (const float*)d_in[10];
    const float* Wp2= (const float*)d_in[11]; const float* bp2= (const float*)d_in[12];

    const int N = in_sizes[0] / F;
    const int E = in_sizes[1] / 2;
    const int G = out_size / 2;
    const int* srcp = ei;
    const int* dstp = ei + E;
    const int eb = (E + 255) / 256;
    const int nb = (N + 255) / 256;

    char* w = (char*)d_ws;
    size_t off = 0;
    auto alloc = [&](size_t bytes) -> void* {
        void* p = w + off;
        off = (off + bytes + 255) & ~(size_t)255;
        return p;
    };

    // ---- primary layout (two-phase scatter/stream) ----
    float*    hA    = (float*)alloc((size_t)N * F * 4);
    float*    hB    = (float*)alloc((size_t)N * F * 4);
    unsigned* msg   = (unsigned*)alloc((size_t)E * F * 2);
    int*  cntd  = (int*)alloc((size_t)N * 4);
    int*  cnts  = (int*)alloc((size_t)N * 4);
    int*  curd  = (int*)alloc((size_t)N * 4);
    int*  curs  = (int*)alloc((size_t)N * 4);
    int*  offs  = (int*)alloc((size_t)(N + 1) * 4);
    int*  soffs = (int*)alloc((size_t)(N + 1) * 4);
    float* dinv = (float*)alloc((size_t)N * 4);
    int2*  csc  = (int2*)alloc((size_t)E * 8);
    float* pooled = (float*)alloc((size_t)G * F * 4);
    size_t need_primary = off;

    if (need_primary <= ws_size) {
        hipMemsetAsync(cntd, 0, (size_t)N * 4, stream);
        hipMemsetAsync(cnts, 0, (size_t)N * 4, stream);
        hipMemsetAsync(curd, 0, (size_t)N * 4, stream);
        hipMemsetAsync(curs, 0, (size_t)N * 4, stream);
        hipMemsetAsync(pooled, 0, (size_t)G * F * 4, stream);

        count2_kernel<<<eb, 256, 0, stream>>>(srcp, dstp, cntd, cnts, E);
        dinv_kernel<<<nb, 256, 0, stream>>>(cntd, dinv, N);
        scan_kernel<<<1, 1024, 0, stream>>>(cntd, offs, N);
        scan_kernel<<<1, 1024, 0, stream>>>(cnts, soffs, N);
        fill2_kernel<<<eb, 256, 0, stream>>>(srcp, dstp, offs, soffs, curd, curs, dinv, csc, E);

        const int pb = 2048;
        dim3 gg(512, 2);
        // L1
        gemm_kernel<false><<<gg, 256, 0, stream>>>(x, W1, hA, N);
        scat_kernel<<<pb, 256, 0, stream>>>((const float2*)hA, soffs, csc, msg, N);
        aggB_kernel<0><<<pb, 256, 0, stream>>>(msg, (const float2*)hA, offs, dinv, b1, hB, nullptr, N);
        // L2
        gemm_kernel<false><<<gg, 256, 0, stream>>>(hB, W2, hA, N);
        scat_kernel<<<pb, 256, 0, stream>>>((const float2*)hA, soffs, csc, msg, N);
        aggB_kernel<0><<<pb, 256, 0, stream>>>(msg, (const float2*)hA, offs, dinv, b2, hB, nullptr, N);
        // L3 + pool
        gemm_kernel<false><<<gg, 256, 0, stream>>>(hB, W3, hA, N);
        scat_kernel<<<pb, 256, 0, stream>>>((const float2*)hA, soffs, csc, msg, N);
        aggB_kernel<1><<<pb, 256, 0, stream>>>(msg, (const float2*)hA, offs, dinv, b3, pooled, batch, N);

        mlp_kernel<<<G, 128, 0, stream>>>(pooled, Wp1, bp1, Wp2, bp2, (float*)d_out);
        return;
    }

    // ---- fallback layout (R7 gather) ----
    off = 0;
    unsigned short* hlb = (unsigned short*)alloc((size_t)N * F * 2);
    float* hbuf   = (float*)alloc((size_t)N * F * 4);
    int*   deg    = (int*)alloc((size_t)N * 4);
    int*   cursor = (int*)alloc((size_t)N * 4);
    int*   foffs  = (int*)alloc((size_t)(N + 1) * 4);
    float* fdinv  = (float*)alloc((size_t)N * 4);
    int2*  csr    = (int2*)alloc((size_t)E * 8);
    float* fpooled= (float*)alloc((size_t)G * F * 4);

    hipMemsetAsync(deg,    0, (size_t)N * 4, stream);
    hipMemsetAsync(cursor, 0, (size_t)N * 4, stream);
    hipMemsetAsync(fpooled, 0, (size_t)G * F * 4, stream);

    count2_kernel<<<eb, 256, 0, stream>>>(srcp, dstp, deg, nullptr, E);
    dinv_kernel<<<nb, 256, 0, stream>>>(deg, fdinv, N);
    scan_kernel<<<1, 1024, 0, stream>>>(deg, foffs, N);
    fill_kernel<<<eb, 256, 0, stream>>>(srcp, dstp, foffs, cursor, fdinv, csr, E);

    const int ab = 2048;
    dim3 gg(512, 2);
    gemm_kernel<true><<<gg, 256, 0, stream>>>(x, W1, hlb, N);
    agg_kernel<0><<<ab, 256, 0, stream>>>((const unsigned*)hlb, foffs, csr, fdinv, b1, hbuf, nullptr, N);
    gemm_kernel<true><<<gg, 256, 0, stream>>>(hbuf, W2, hlb, N);
    agg_kernel<0><<<ab, 256, 0, stream>>>((const unsigned*)hlb, foffs, csr, fdinv, b2, hbuf, nullptr, N);
    gemm_kernel<true><<<gg, 256, 0, stream>>>(hbuf, W3, hlb, N);
    agg_kernel<1><<<ab, 256, 0, stream>>>((const unsigned*)hlb, foffs, csr, fdinv, b3, fpooled, batch, N);
    mlp_kernel<<<G, 128, 0, stream>>>(fpooled, Wp1, bp1, Wp2, bp2, (float*)d_out);
}

// Round 9
// 1008.459 us; speedup vs baseline: 1.3595x; 1.1440x over previous
//
#include <hip/hip_runtime.h>

#define F 128
#define BN 64

// ---------------- CSR build ----------------

__global__ __launch_bounds__(256) void count_kernel(const int* __restrict__ dst,
                                                    int* __restrict__ cnt, int e) {
    int i = blockIdx.x * 256 + threadIdx.x;
    if (i < e) atomicAdd(&cnt[dst[i]], 1);
}

__global__ __launch_bounds__(256) void dinv_kernel(const int* __restrict__ cnt,
                                                   float* __restrict__ dinv, int n) {
    int i = blockIdx.x * 256 + threadIdx.x;
    if (i < n) dinv[i] = rsqrtf((float)(cnt[i] + 1));  // +1 self loop
}

__global__ __launch_bounds__(1024) void scan_kernel(const int* __restrict__ cnt,
                                                    int* __restrict__ offs, int n) {
    __shared__ int sm[1024];
    int tid = threadIdx.x;
    int chunk = (n + 1023) >> 10;
    int b = tid * chunk;
    int e = b + chunk; if (e > n) e = n;
    int s = 0;
    for (int i = b; i < e; i++) s += cnt[i];
    sm[tid] = s;
    __syncthreads();
    for (int d = 1; d < 1024; d <<= 1) {
        int v = 0;
        if (tid >= d) v = sm[tid - d];
        __syncthreads();
        if (tid >= d) sm[tid] += v;
        __syncthreads();
    }
    int run = (tid == 0) ? 0 : sm[tid - 1];
    for (int i = b; i < e; i++) { offs[i] = run; run += cnt[i]; }
    if (tid == 1023) offs[n] = sm[1023];
}

__global__ __launch_bounds__(256) void fill_kernel(const int* __restrict__ src,
                                                   const int* __restrict__ dst,
                                                   const int* __restrict__ offs,
                                                   int* __restrict__ cursor,
                                                   const float* __restrict__ dinv,
                                                   int2* __restrict__ csr, int e) {
    int i = blockIdx.x * 256 + threadIdx.x;
    if (i >= e) return;
    int s = src[i], d = dst[i];
    int pos = atomicAdd(&cursor[d], 1);
    csr[offs[d] + pos] = make_int2(s, __float_as_int(dinv[s] * dinv[d]));
}

// ---------------- bf16 helpers ----------------

__device__ __forceinline__ unsigned short f32_to_bf16_rne(float x) {
    unsigned u = __float_as_uint(x);
    unsigned r = (u + 0x7fffu + ((u >> 16) & 1u)) >> 16;   // round to nearest even
    return (unsigned short)r;
}

__device__ __forceinline__ float bfhi(unsigned v) { return __uint_as_float(v & 0xffff0000u); }
__device__ __forceinline__ float bflo(unsigned v) { return __uint_as_float(v << 16); }

// ---------------- GEMM: outb[n][128](bf16) = h[n][128](f32) @ W[128][128] ----------------

__global__ __launch_bounds__(256) void gemm_kernel(const float* __restrict__ h,
                                                   const float* __restrict__ W,
                                                   unsigned short* __restrict__ outb, int n) {
    __shared__ float Ws[128 * 64];   // Ws[k][fh]
    __shared__ float Hs[BN * 128];   // Hs[nn][k ^ ((nn&7)<<2)]  (bank swizzle)
    const int tid = threadIdx.x;
    const int half = blockIdx.y;

    for (int i = tid; i < 128 * 64; i += 256) {
        int k = i >> 6, fh = i & 63;
        Ws[i] = W[k * F + (half << 6) + fh];
    }

    const int fg = tid & 15;
    const int ng = tid >> 4;
    const int f0 = fg << 2;
    const int n0 = ng << 2;
    const int nchunk = (n + BN - 1) / BN;

    for (int c = blockIdx.x; c < nchunk; c += gridDim.x) {
        const int base = c * BN;
        __syncthreads();
        for (int i = tid; i < BN * 128; i += 256) {
            int nn = i >> 7, k = i & 127;
            int node = base + nn;
            float v = (node < n) ? h[(size_t)node * F + k] : 0.0f;
            Hs[(nn << 7) + (k ^ ((nn & 7) << 2))] = v;
        }
        __syncthreads();

        float acc[4][4];
        #pragma unroll
        for (int a = 0; a < 4; a++)
            #pragma unroll
            for (int b = 0; b < 4; b++) acc[a][b] = 0.0f;

        #pragma unroll 2
        for (int kk = 0; kk < 128; kk += 4) {
            float4 w0 = *(const float4*)&Ws[((kk + 0) << 6) + f0];
            float4 w1 = *(const float4*)&Ws[((kk + 1) << 6) + f0];
            float4 w2 = *(const float4*)&Ws[((kk + 2) << 6) + f0];
            float4 w3 = *(const float4*)&Ws[((kk + 3) << 6) + f0];
            #pragma unroll
            for (int j = 0; j < 4; j++) {
                const int nn = n0 + j;
                float4 hv = *(const float4*)&Hs[(nn << 7) + (kk ^ ((nn & 7) << 2))];
                acc[j][0] += hv.x * w0.x + hv.y * w1.x + hv.z * w2.x + hv.w * w3.x;
                acc[j][1] += hv.x * w0.y + hv.y * w1.y + hv.z * w2.y + hv.w * w3.y;
                acc[j][2] += hv.x * w0.z + hv.y * w1.z + hv.z * w2.z + hv.w * w3.z;
                acc[j][3] += hv.x * w0.w + hv.y * w1.w + hv.z * w2.w + hv.w * w3.w;
            }
        }

        #pragma unroll
        for (int j = 0; j < 4; j++) {
            int node = base + n0 + j;
            if (node < n) {
                ushort4 v;
                v.x = f32_to_bf16_rne(acc[j][0]);
                v.y = f32_to_bf16_rne(acc[j][1]);
                v.z = f32_to_bf16_rne(acc[j][2]);
                v.w = f32_to_bf16_rne(acc[j][3]);
                *(ushort4*)&outb[(size_t)node * F + (half << 6) + f0] = v;
            }
        }
    }
}

// ---------------- Aggregate: persistent wave-per-node; SCALAR csr/offs loads ----------------
// Wave index forced uniform via readfirstlane so offs/csr/dinv/batch loads become
// s_load (scalar cache) and row-load addresses are SGPR-base + lane offset.
// Row loads (vector path) are the only vector-memory traffic in the loop.

template <int POOL>
__global__ __launch_bounds__(256) void agg_kernel(const unsigned* __restrict__ hlb,
                                                  const int* __restrict__ offs,
                                                  const int2* __restrict__ csr,
                                                  const float* __restrict__ dinv,
                                                  const float* __restrict__ bias,
                                                  float* __restrict__ out,
                                                  const int* __restrict__ batch, int n) {
    const int lane = threadIdx.x & 63;
    const int wlocal = __builtin_amdgcn_readfirstlane(threadIdx.x >> 6);  // uniform wave id in block
    const int wstart = blockIdx.x * 4 + wlocal;
    const int wstride = gridDim.x * 4;
    const unsigned* __restrict__ rowp = hlb + lane;
    const float2 bv = ((const float2*)bias)[lane];

    for (int i = wstart; i < n; i += wstride) {
        float ax = 0.0f, ay = 0.0f;
        const int e0 = offs[i], e1 = offs[i + 1];
        int nb = (e1 - e0) >> 3;            // number of full 8-batches

        int2 cc0, cc1, cc2, cc3, cc4, cc5, cc6, cc7;
        int e = e0;
        if (nb > 0) {                       // prologue: csr batch 0 (scalar loads)
            cc0 = csr[e + 0]; cc1 = csr[e + 1]; cc2 = csr[e + 2]; cc3 = csr[e + 3];
            cc4 = csr[e + 4]; cc5 = csr[e + 5]; cc6 = csr[e + 6]; cc7 = csr[e + 7];
        }
        for (int b = 0; b < nb; b++) {
            // issue row loads for current batch (SGPR base + lane*4)
            unsigned r0 = rowp[(size_t)cc0.x << 6];
            unsigned r1 = rowp[(size_t)cc1.x << 6];
            unsigned r2 = rowp[(size_t)cc2.x << 6];
            unsigned r3 = rowp[(size_t)cc3.x << 6];
            unsigned r4 = rowp[(size_t)cc4.x << 6];
            unsigned r5 = rowp[(size_t)cc5.x << 6];
            unsigned r6 = rowp[(size_t)cc6.x << 6];
            unsigned r7 = rowp[(size_t)cc7.x << 6];
            float n0 = __int_as_float(cc0.y), n1 = __int_as_float(cc1.y);
            float n2 = __int_as_float(cc2.y), n3 = __int_as_float(cc3.y);
            float n4 = __int_as_float(cc4.y), n5 = __int_as_float(cc5.y);
            float n6 = __int_as_float(cc6.y), n7 = __int_as_float(cc7.y);
            // prefetch next batch's csr (scalar) before consuming rows
            e += 8;
            if (b + 1 < nb) {
                cc0 = csr[e + 0]; cc1 = csr[e + 1]; cc2 = csr[e + 2]; cc3 = csr[e + 3];
                cc4 = csr[e + 4]; cc5 = csr[e + 5]; cc6 = csr[e + 6]; cc7 = csr[e + 7];
            }
            // consume rows
            ax += bflo(r0) * n0 + bflo(r1) * n1 + bflo(r2) * n2 + bflo(r3) * n3
                + bflo(r4) * n4 + bflo(r5) * n5 + bflo(r6) * n6 + bflo(r7) * n7;
            ay += bfhi(r0) * n0 + bfhi(r1) * n1 + bfhi(r2) * n2 + bfhi(r3) * n3
                + bfhi(r4) * n4 + bfhi(r5) * n5 + bfhi(r6) * n6 + bfhi(r7) * n7;
        }
        // remainder
        for (; e < e1; e++) {
            int2 c = csr[e];
            unsigned r = rowp[(size_t)c.x << 6];
            float nf = __int_as_float(c.y);
            ax += bflo(r) * nf;
            ay += bfhi(r) * nf;
        }
        // self loop
        {
            float di = dinv[i];
            unsigned r = rowp[(size_t)i << 6];
            ax += bflo(r) * di * di;
            ay += bfhi(r) * di * di;
        }

        float rx = fmaxf(ax + bv.x, 0.0f);
        float ry = fmaxf(ay + bv.y, 0.0f);
        if (POOL) {
            int g = batch[i];
            atomicMax((int*)&out[(size_t)g * F + 2 * lane + 0], __float_as_int(rx));
            atomicMax((int*)&out[(size_t)g * F + 2 * lane + 1], __float_as_int(ry));
        } else {
            ((float2*)out)[(size_t)i * 64 + lane] = make_float2(rx, ry);
        }
    }
}

// ---------------- MLP head + log_softmax ----------------

__global__ __launch_bounds__(128) void mlp_kernel(const float* __restrict__ pooled,
                                                  const float* __restrict__ Wp1,
                                                  const float* __restrict__ bp1,
                                                  const float* __restrict__ Wp2,
                                                  const float* __restrict__ bp2,
                                                  float* __restrict__ out) {
    __shared__ float pl[F];
    __shared__ float s0[2], s1[2];
    int g = blockIdx.x, t = threadIdx.x;
    pl[t] = pooled[(size_t)g * F + t];
    __syncthreads();
    float a = bp1[t];
    #pragma unroll 8
    for (int k = 0; k < F; k++) a += pl[k] * Wp1[k * F + t];
    float p0 = a * Wp2[t * 2 + 0];
    float p1 = a * Wp2[t * 2 + 1];
    #pragma unroll
    for (int d = 32; d > 0; d >>= 1) {
        p0 += __shfl_down(p0, d, 64);
        p1 += __shfl_down(p1, d, 64);
    }
    if ((t & 63) == 0) { s0[t >> 6] = p0; s1[t >> 6] = p1; }
    __syncthreads();
    if (t == 0) {
        float l0 = s0[0] + s0[1] + bp2[0];
        float l1 = s1[0] + s1[1] + bp2[1];
        float m = fmaxf(l0, l1);
        float lse = m + logf(expf(l0 - m) + expf(l1 - m));
        out[g * 2 + 0] = l0 - lse;
        out[g * 2 + 1] = l1 - lse;
    }
}

// ---------------- launch ----------------

extern "C" void kernel_launch(void* const* d_in, const int* in_sizes, int n_in,
                              void* d_out, int out_size, void* d_ws, size_t ws_size,
                              hipStream_t stream) {
    const float* x    = (const float*)d_in[0];
    const int*   ei   = (const int*)d_in[1];
    const int*   batch= (const int*)d_in[2];
    const float* W1 = (const float*)d_in[3];  const float* b1 = (const float*)d_in[4];
    const float* W2 = (const float*)d_in[5];  const float* b2 = (const float*)d_in[6];
    const float* W3 = (const float*)d_in[7];  const float* b3 = (const float*)d_in[8];
    const float* Wp1= (const float*)d_in[9];  const float* bp1= (const float*)d_in[10];
    const float* Wp2= (const float*)d_in[11]; const float* bp2= (const float*)d_in[12];

    const int N = in_sizes[0] / F;
    const int E = in_sizes[1] / 2;
    const int G = out_size / 2;

    char* w = (char*)d_ws;
    size_t off = 0;
    auto alloc = [&](size_t bytes) -> void* {
        void* p = w + off;
        off = (off + bytes + 255) & ~(size_t)255;
        return p;
    };
    unsigned short* hlb = (unsigned short*)alloc((size_t)N * F * 2);  // bf16 GEMM out
    float* hbuf   = (float*)alloc((size_t)N * F * 4);                 // f32 agg out
    int*   deg    = (int*)alloc((size_t)N * 4);
    int*   cursor = (int*)alloc((size_t)N * 4);
    int*   offs   = (int*)alloc((size_t)(N + 1) * 4);
    float* dinv   = (float*)alloc((size_t)N * 4);
    int2*  csr    = (int2*)alloc((size_t)E * 8);
    float* pooled = (float*)alloc((size_t)G * F * 4);

    const int* srcp = ei;
    const int* dstp = ei + E;

    hipMemsetAsync(deg,    0, (size_t)N * 4, stream);
    hipMemsetAsync(cursor, 0, (size_t)N * 4, stream);
    hipMemsetAsync(pooled, 0, (size_t)G * F * 4, stream);

    const int eb = (E + 255) / 256;
    const int nb = (N + 255) / 256;
    count_kernel<<<eb, 256, 0, stream>>>(dstp, deg, E);
    dinv_kernel<<<nb, 256, 0, stream>>>(deg, dinv, N);
    scan_kernel<<<1, 1024, 0, stream>>>(deg, offs, N);
    fill_kernel<<<eb, 256, 0, stream>>>(srcp, dstp, offs, cursor, dinv, csr, E);

    const int ab = 2048;   // persistent: 8 blocks/CU * 256 CUs
    dim3 gg(512, 2);
    gemm_kernel<<<gg, 256, 0, stream>>>(x, W1, hlb, N);
    agg_kernel<0><<<ab, 256, 0, stream>>>((const unsigned*)hlb, offs, csr, dinv, b1, hbuf, nullptr, N);
    gemm_kernel<<<gg, 256, 0, stream>>>(hbuf, W2, hlb, N);
    agg_kernel<0><<<ab, 256, 0, stream>>>((const unsigned*)hlb, offs, csr, dinv, b2, hbuf, nullptr, N);
    gemm_kernel<<<gg, 256, 0, stream>>>(hbuf, W3, hlb, N);
    agg_kernel<1><<<ab, 256, 0, stream>>>((const unsigned*)hlb, offs, csr, dinv, b3, pooled, batch, N);
    mlp_kernel<<<G, 128, 0, stream>>>(pooled, Wp1, bp1, Wp2, bp2, (float*)d_out);
}

// Round 10
// 766.161 us; speedup vs baseline: 1.7894x; 1.3163x over previous
//
#include <hip/hip_runtime.h>

#define F 128

typedef __attribute__((ext_vector_type(8))) short bf16x8;
typedef __attribute__((ext_vector_type(4))) float f32x4;

// ---------------- CSR build ----------------

__global__ __launch_bounds__(256) void count_kernel(const int* __restrict__ dst,
                                                    int* __restrict__ cnt, int e) {
    int i = blockIdx.x * 256 + threadIdx.x;
    if (i < e) atomicAdd(&cnt[dst[i]], 1);
}

__global__ __launch_bounds__(256) void dinv_kernel(const int* __restrict__ cnt,
                                                   float* __restrict__ dinv, int n) {
    int i = blockIdx.x * 256 + threadIdx.x;
    if (i < n) dinv[i] = rsqrtf((float)(cnt[i] + 1));  // +1 self loop
}

__global__ __launch_bounds__(1024) void scan_kernel(const int* __restrict__ cnt,
                                                    int* __restrict__ offs, int n) {
    __shared__ int sm[1024];
    int tid = threadIdx.x;
    int chunk = (n + 1023) >> 10;
    int b = tid * chunk;
    int e = b + chunk; if (e > n) e = n;
    int s = 0;
    for (int i = b; i < e; i++) s += cnt[i];
    sm[tid] = s;
    __syncthreads();
    for (int d = 1; d < 1024; d <<= 1) {
        int v = 0;
        if (tid >= d) v = sm[tid - d];
        __syncthreads();
        if (tid >= d) sm[tid] += v;
        __syncthreads();
    }
    int run = (tid == 0) ? 0 : sm[tid - 1];
    for (int i = b; i < e; i++) { offs[i] = run; run += cnt[i]; }
    if (tid == 1023) offs[n] = sm[1023];
}

__global__ __launch_bounds__(256) void fill_kernel(const int* __restrict__ src,
                                                   const int* __restrict__ dst,
                                                   const int* __restrict__ offs,
                                                   int* __restrict__ cursor,
                                                   const float* __restrict__ dinv,
                                                   int2* __restrict__ csr, int e) {
    int i = blockIdx.x * 256 + threadIdx.x;
    if (i >= e) return;
    int s = src[i], d = dst[i];
    int pos = atomicAdd(&cursor[d], 1);
    csr[offs[d] + pos] = make_int2(s, __float_as_int(dinv[s] * dinv[d]));
}

// ---------------- bf16 helpers ----------------

__device__ __forceinline__ unsigned short f32_to_bf16_rne(float x) {
    unsigned u = __float_as_uint(x);
    unsigned r = (u + 0x7fffu + ((u >> 16) & 1u)) >> 16;   // round to nearest even
    return (unsigned short)r;
}

__device__ __forceinline__ float bfhi(unsigned v) { return __uint_as_float(v & 0xffff0000u); }
__device__ __forceinline__ float bflo(unsigned v) { return __uint_as_float(v << 16); }

// ---------------- converts ----------------

__global__ __launch_bounds__(256) void cvtx_kernel(const float4* __restrict__ x4,
                                                   ushort4* __restrict__ xb4, long n4) {
    long stride = (long)gridDim.x * 256;
    for (long i = blockIdx.x * 256 + threadIdx.x; i < n4; i += stride) {
        float4 v = x4[i];
        ushort4 o;
        o.x = f32_to_bf16_rne(v.x);
        o.y = f32_to_bf16_rne(v.y);
        o.z = f32_to_bf16_rne(v.z);
        o.w = f32_to_bf16_rne(v.w);
        xb4[i] = o;
    }
}

// Wt[c][k] = bf16(W[k][c]); one matrix per launch. grid=128 (c), block=128 (k)
__global__ __launch_bounds__(128) void cvtw_kernel(const float* __restrict__ W,
                                                   unsigned short* __restrict__ Wt) {
    int c = blockIdx.x, k = threadIdx.x;
    Wt[c * F + k] = f32_to_bf16_rne(W[k * F + c]);
}

// ---------------- MFMA GEMM: outb[n][128](bf16) = hb[n][128](bf16) @ W ----------------
// Wt is transposed bf16 weights [col][k]. Block=256 (4 waves), wave = 16 rows.
// A frag: row=lane&15, k=(lane>>4)*8+i.  B frag: col=lane&15, k=(lane>>4)*8+i.
// D frag: col=lane&15, row=(lane>>4)*4+j (m89-verified).

__global__ __launch_bounds__(256) void gemm_mfma(const unsigned short* __restrict__ hb,
                                                 const unsigned short* __restrict__ Wt,
                                                 unsigned short* __restrict__ outb, int n) {
    __shared__ unsigned short sm[4][16][F];
    const int tid = threadIdx.x;
    const int w = tid >> 6, lane = tid & 63;
    const int r = lane & 15, kg = lane >> 4;
    const long base = (long)blockIdx.x * 64 + w * 16;

    int arow = (int)(base + r);
    if (arow >= n) arow = n - 1;                      // clamp (write is guarded)
    const bf16x8* __restrict__ arowp = (const bf16x8*)(hb + (size_t)arow * F);

    f32x4 acc[8] = {};
    #pragma unroll
    for (int c = 0; c < 4; c++) {
        bf16x8 a = arowp[c * 4 + kg];                 // k0 = c*32 + kg*8
        #pragma unroll
        for (int t = 0; t < 8; t++) {
            bf16x8 b = *(const bf16x8*)(Wt + (size_t)(t * 16 + r) * F + c * 32 + kg * 8);
            acc[t] = __builtin_amdgcn_mfma_f32_16x16x32_bf16(a, b, acc[t], 0, 0, 0);
        }
    }

    // repack D -> row-major bf16 via wave-local LDS slice
    #pragma unroll
    for (int t = 0; t < 8; t++)
        #pragma unroll
        for (int j = 0; j < 4; j++)
            sm[w][kg * 4 + j][t * 16 + r] = f32_to_bf16_rne(acc[t][j]);
    // same-wave write->read: compiler inserts lgkmcnt wait; no barrier needed
    #pragma unroll
    for (int it = 0; it < 4; it++) {
        int row = it * 4 + kg;
        long grow = base + row;
        if (grow < n) {
            uint4 v = *(uint4*)&sm[w][row][r * 8];
            *(uint4*)(outb + (size_t)grow * F + r * 8) = v;
        }
    }
}

// ---------------- Aggregate: persistent wave-per-node; scalar csr; bf16 in/out ----------

template <int POOL>
__global__ __launch_bounds__(256) void agg_kernel(const unsigned* __restrict__ hlb,
                                                  const int* __restrict__ offs,
                                                  const int2* __restrict__ csr,
                                                  const float* __restrict__ dinv,
                                                  const float* __restrict__ bias,
                                                  void* __restrict__ outp,
                                                  const int* __restrict__ batch, int n) {
    const int lane = threadIdx.x & 63;
    const int wlocal = __builtin_amdgcn_readfirstlane(threadIdx.x >> 6);
    const int wstart = blockIdx.x * 4 + wlocal;
    const int wstride = gridDim.x * 4;
    const unsigned* __restrict__ rowp = hlb + lane;
    const float2 bv = ((const float2*)bias)[lane];

    for (int i = wstart; i < n; i += wstride) {
        float ax = 0.0f, ay = 0.0f;
        const int e0 = offs[i], e1 = offs[i + 1];
        int nb = (e1 - e0) >> 3;

        int2 cc0, cc1, cc2, cc3, cc4, cc5, cc6, cc7;
        int e = e0;
        if (nb > 0) {
            cc0 = csr[e + 0]; cc1 = csr[e + 1]; cc2 = csr[e + 2]; cc3 = csr[e + 3];
            cc4 = csr[e + 4]; cc5 = csr[e + 5]; cc6 = csr[e + 6]; cc7 = csr[e + 7];
        }
        for (int b = 0; b < nb; b++) {
            unsigned r0 = rowp[(size_t)cc0.x << 6];
            unsigned r1 = rowp[(size_t)cc1.x << 6];
            unsigned r2 = rowp[(size_t)cc2.x << 6];
            unsigned r3 = rowp[(size_t)cc3.x << 6];
            unsigned r4 = rowp[(size_t)cc4.x << 6];
            unsigned r5 = rowp[(size_t)cc5.x << 6];
            unsigned r6 = rowp[(size_t)cc6.x << 6];
            unsigned r7 = rowp[(size_t)cc7.x << 6];
            float n0 = __int_as_float(cc0.y), n1 = __int_as_float(cc1.y);
            float n2 = __int_as_float(cc2.y), n3 = __int_as_float(cc3.y);
            float n4 = __int_as_float(cc4.y), n5 = __int_as_float(cc5.y);
            float n6 = __int_as_float(cc6.y), n7 = __int_as_float(cc7.y);
            e += 8;
            if (b + 1 < nb) {
                cc0 = csr[e + 0]; cc1 = csr[e + 1]; cc2 = csr[e + 2]; cc3 = csr[e + 3];
                cc4 = csr[e + 4]; cc5 = csr[e + 5]; cc6 = csr[e + 6]; cc7 = csr[e + 7];
            }
            ax += bflo(r0) * n0 + bflo(r1) * n1 + bflo(r2) * n2 + bflo(r3) * n3
                + bflo(r4) * n4 + bflo(r5) * n5 + bflo(r6) * n6 + bflo(r7) * n7;
            ay += bfhi(r0) * n0 + bfhi(r1) * n1 + bfhi(r2) * n2 + bfhi(r3) * n3
                + bfhi(r4) * n4 + bfhi(r5) * n5 + bfhi(r6) * n6 + bfhi(r7) * n7;
        }
        for (; e < e1; e++) {
            int2 c = csr[e];
            unsigned r = rowp[(size_t)c.x << 6];
            float nf = __int_as_float(c.y);
            ax += bflo(r) * nf;
            ay += bfhi(r) * nf;
        }
        {
            float di = dinv[i];
            unsigned r = rowp[(size_t)i << 6];
            ax += bflo(r) * di * di;
            ay += bfhi(r) * di * di;
        }

        float rx = fmaxf(ax + bv.x, 0.0f);
        float ry = fmaxf(ay + bv.y, 0.0f);
        if (POOL) {
            float* out = (float*)outp;
            int g = batch[i];
            atomicMax((int*)&out[(size_t)g * F + 2 * lane + 0], __float_as_int(rx));
            atomicMax((int*)&out[(size_t)g * F + 2 * lane + 1], __float_as_int(ry));
        } else {
            unsigned lo = f32_to_bf16_rne(rx);
            unsigned hi = f32_to_bf16_rne(ry);
            ((unsigned*)outp)[(size_t)i * 64 + lane] = lo | (hi << 16);
        }
    }
}

// ---------------- MLP head + log_softmax ----------------

__global__ __launch_bounds__(128) void mlp_kernel(const float* __restrict__ pooled,
                                                  const float* __restrict__ Wp1,
                                                  const float* __restrict__ bp1,
                                                  const float* __restrict__ Wp2,
                                                  const float* __restrict__ bp2,
                                                  float* __restrict__ out) {
    __shared__ float pl[F];
    __shared__ float s0[2], s1[2];
    int g = blockIdx.x, t = threadIdx.x;
    pl[t] = pooled[(size_t)g * F + t];
    __syncthreads();
    float a = bp1[t];
    #pragma unroll 8
    for (int k = 0; k < F; k++) a += pl[k] * Wp1[k * F + t];
    float p0 = a * Wp2[t * 2 + 0];
    float p1 = a * Wp2[t * 2 + 1];
    #pragma unroll
    for (int d = 32; d > 0; d >>= 1) {
        p0 += __shfl_down(p0, d, 64);
        p1 += __shfl_down(p1, d, 64);
    }
    if ((t & 63) == 0) { s0[t >> 6] = p0; s1[t >> 6] = p1; }
    __syncthreads();
    if (t == 0) {
        float l0 = s0[0] + s0[1] + bp2[0];
        float l1 = s1[0] + s1[1] + bp2[1];
        float m = fmaxf(l0, l1);
        float lse = m + logf(expf(l0 - m) + expf(l1 - m));
        out[g * 2 + 0] = l0 - lse;
        out[g * 2 + 1] = l1 - lse;
    }
}

// ---------------- launch ----------------

extern "C" void kernel_launch(void* const* d_in, const int* in_sizes, int n_in,
                              void* d_out, int out_size, void* d_ws, size_t ws_size,
                              hipStream_t stream) {
    const float* x    = (const float*)d_in[0];
    const int*   ei   = (const int*)d_in[1];
    const int*   batch= (const int*)d_in[2];
    const float* W1 = (const float*)d_in[3];  const float* b1 = (const float*)d_in[4];
    const float* W2 = (const float*)d_in[5];  const float* b2 = (const float*)d_in[6];
    const float* W3 = (const float*)d_in[7];  const float* b3 = (const float*)d_in[8];
    const float* Wp1= (const float*)d_in[9];  const float* bp1= (const float*)d_in[10];
    const float* Wp2= (const float*)d_in[11]; const float* bp2= (const float*)d_in[12];

    const int N = in_sizes[0] / F;
    const int E = in_sizes[1] / 2;
    const int G = out_size / 2;

    char* w = (char*)d_ws;
    size_t off = 0;
    auto alloc = [&](size_t bytes) -> void* {
        void* p = w + off;
        off = (off + bytes + 255) & ~(size_t)255;
        return p;
    };
    unsigned short* xb  = (unsigned short*)alloc((size_t)N * F * 2);  // bf16 input
    unsigned short* hlb = (unsigned short*)alloc((size_t)N * F * 2);  // bf16 GEMM out
    unsigned short* hab = (unsigned short*)alloc((size_t)N * F * 2);  // bf16 agg out
    unsigned short* Wt1 = (unsigned short*)alloc((size_t)F * F * 2);
    unsigned short* Wt2 = (unsigned short*)alloc((size_t)F * F * 2);
    unsigned short* Wt3 = (unsigned short*)alloc((size_t)F * F * 2);
    int*   deg    = (int*)alloc((size_t)N * 4);
    int*   cursor = (int*)alloc((size_t)N * 4);
    int*   offs   = (int*)alloc((size_t)(N + 1) * 4);
    float* dinv   = (float*)alloc((size_t)N * 4);
    int2*  csr    = (int2*)alloc((size_t)E * 8);
    float* pooled = (float*)alloc((size_t)G * F * 4);

    const int* srcp = ei;
    const int* dstp = ei + E;

    hipMemsetAsync(deg,    0, (size_t)N * 4, stream);
    hipMemsetAsync(cursor, 0, (size_t)N * 4, stream);
    hipMemsetAsync(pooled, 0, (size_t)G * F * 4, stream);

    const int eb = (E + 255) / 256;
    const int nb = (N + 255) / 256;
    cvtx_kernel<<<2048, 256, 0, stream>>>((const float4*)x, (ushort4*)xb, (long)N * F / 4);
    cvtw_kernel<<<F, F, 0, stream>>>(W1, Wt1);
    cvtw_kernel<<<F, F, 0, stream>>>(W2, Wt2);
    cvtw_kernel<<<F, F, 0, stream>>>(W3, Wt3);
    count_kernel<<<eb, 256, 0, stream>>>(dstp, deg, E);
    dinv_kernel<<<nb, 256, 0, stream>>>(deg, dinv, N);
    scan_kernel<<<1, 1024, 0, stream>>>(deg, offs, N);
    fill_kernel<<<eb, 256, 0, stream>>>(srcp, dstp, offs, cursor, dinv, csr, E);

    const int gb = (N + 63) / 64;
    const int ab = 2048;   // persistent: 8 blocks/CU * 256 CUs
    gemm_mfma<<<gb, 256, 0, stream>>>(xb, Wt1, hlb, N);
    agg_kernel<0><<<ab, 256, 0, stream>>>((const unsigned*)hlb, offs, csr, dinv, b1, hab, nullptr, N);
    gemm_mfma<<<gb, 256, 0, stream>>>(hab, Wt2, hlb, N);
    agg_kernel<0><<<ab, 256, 0, stream>>>((const unsigned*)hlb, offs, csr, dinv, b2, hab, nullptr, N);
    gemm_mfma<<<gb, 256, 0, stream>>>(hab, Wt3, hlb, N);
    agg_kernel<1><<<ab, 256, 0, stream>>>((const unsigned*)hlb, offs, csr, dinv, b3, pooled, batch, N);
    mlp_kernel<<<G, 128, 0, stream>>>(pooled, Wp1, bp1, Wp2, bp2, (float*)d_out);
}